// Round 15
// baseline (74.759 us; speedup 1.0000x reference)
//
#include <hip/hip_runtime.h>
#include <math.h>

#define BINS 10
#define K1_THREADS 256

typedef float f32x4 __attribute__((ext_vector_type(4)));
typedef int   i32x4 __attribute__((ext_vector_type(4)));

// Cumulative-threshold formulation in LOG2 space:
//   t = xs * log2(e);  bin >= b  <=>  t >= TH2[b] = log2(b/(10-b))
//   softplus(xs) = ln2 * [ max(t,0) + log2(1 + 2^(-|t|)) ]  = ln2 * bce2
// We accumulate bce2 (scaled) and multiply the final scalar by ln2 in k2.
// Invalid elements poisoned t=-1e30: bce2 == 0 exactly, fails all thresholds.
// exp2f/log2f are the NATIVE v_exp_f32/v_log_f32 ops (no range-scaling mul).
// NOTE: this ghm_elem body (bool ge + ternary adds, float accumulators) is
// the ONLY idiom set that passes on this toolchain — float-mask+fmaf (R9-R11)
// and unsigned+=bool (R14) both SIGABRT the harness. Do not deviate.
__device__ __forceinline__ void ghm_elem(int y, float x, float w,
                                         float* __restrict__ G,
                                         float* __restrict__ C) {
    constexpr float TH2[10] = {
        0.0f,
        -3.16992500f,    // log2(1/9)
        -2.0f,           // log2(2/8)
        -1.22239242f,    // log2(3/7)
        -0.58496250f,    // log2(4/6)
         0.0f,           // log2(5/5)
         0.58496250f,
         1.22239242f,
         2.0f,
         3.16992500f };
    float t = x * 1.44269504f;                   // x * log2(e)
    t = __int_as_float(__float_as_int(t) ^ (y << 31));  // label==1 -> -t
    bool v = (w > 0.0f);
    t = v ? t : -1e30f;
    C[0] += v ? 1.0f : 0.0f;
    float e2   = exp2f(-fabsf(t));               // v_exp_f32, src mods fold
    float bce2 = fmaxf(t, 0.0f) + log2f(1.0f + e2);   // v_log_f32
    G[0] += bce2;
    #pragma unroll
    for (int b = 1; b < BINS; ++b) {
        bool ge = (t >= TH2[b]);
        C[b] += ge ? 1.0f : 0.0f;
        G[b] += ge ? bce2 : 0.0f;
    }
}

// Inline-asm loads: the compiler CANNOT sink these to their uses, so the
// depth-3 pipeline actually stays in flight (R8-proven structure).
#define GLOAD(dst, ptr) \
    asm volatile("global_load_dwordx4 %0, %1, off" : "=v"(dst) : "v"(ptr))

// Counted drain + scheduling fence (rule #18).
#define VMWAIT(N)                                              \
    do { asm volatile("s_waitcnt vmcnt(" #N ")" ::: "memory"); \
         __builtin_amdgcn_sched_barrier(0); } while (0)

#define CONSUME(l, xv, wv)                        \
    do {                                          \
        ghm_elem(l[0], xv[0], wv[0], G, C);       \
        ghm_elem(l[1], xv[1], wv[1], G, C);       \
        ghm_elem(l[2], xv[2], wv[2], G, C);       \
        ghm_elem(l[3], xv[3], wv[3], G, C);       \
    } while (0)

__global__ __launch_bounds__(K1_THREADS, 6) void ghm_partial(
    const int*   __restrict__ labels,
    const float* __restrict__ logits,
    const float* __restrict__ weights,
    float*       __restrict__ partial,
    int n4, int n, int nb)
{
    const int tid = blockIdx.x * K1_THREADS + threadIdx.x;
    const int T   = gridDim.x * K1_THREADS;

    float G[BINS], C[BINS];
    #pragma unroll
    for (int b = 0; b < BINS; ++b) { G[b] = 0.0f; C[b] = 0.0f; }

    const i32x4* lab4 = (const i32x4*)labels;
    const f32x4* log4 = (const f32x4*)logits;
    const f32x4* w4   = (const f32x4*)weights;

    const int nfull = n4 / T;      // uniform full batches per thread
    int consumed = 0;

    if (nfull >= 3) {
        i32x4 lA, lB, lC;
        f32x4 xA, xB, xC, wA, wB, wC;
        long ia = tid;
        // prologue: 3 batches x 3 streams = 9 loads in flight
        GLOAD(lA, lab4 + ia);         GLOAD(xA, log4 + ia);         GLOAD(wA, w4 + ia);
        GLOAD(lB, lab4 + ia + T);     GLOAD(xB, log4 + ia + T);     GLOAD(wB, w4 + ia + T);
        GLOAD(lC, lab4 + ia + 2*T);   GLOAD(xC, log4 + ia + 2*T);   GLOAD(wC, w4 + ia + 2*T);

        const int s = (nfull - 3) / 3;    // steady iterations (3 batches each)
        long inx = ia + 3L * T;           // next issue index
        for (int it = 0; it < s; ++it) {
            VMWAIT(6);                    // oldest 3 (A) drained
            CONSUME(lA, xA, wA);
            GLOAD(lA, lab4 + inx); GLOAD(xA, log4 + inx); GLOAD(wA, w4 + inx);
            inx += T;
            VMWAIT(6);                    // B drained
            CONSUME(lB, xB, wB);
            GLOAD(lB, lab4 + inx); GLOAD(xB, log4 + inx); GLOAD(wB, w4 + inx);
            inx += T;
            VMWAIT(6);                    // C drained
            CONSUME(lC, xC, wC);
            GLOAD(lC, lab4 + inx); GLOAD(xC, log4 + inx); GLOAD(wC, w4 + inx);
            inx += T;
        }
        VMWAIT(6); CONSUME(lA, xA, wA);
        VMWAIT(3); CONSUME(lB, xB, wB);
        VMWAIT(0); CONSUME(lC, xC, wC);   // all drained -> clean vmcnt state
        consumed = 3 + 3 * s;
    }

    // leftover batches (ragged region when n4 % T != 0) — plain loads
    for (long i2 = (long)tid + (long)consumed * T; i2 < n4; i2 += T) {
        i32x4 lb = lab4[i2];
        f32x4 xv = log4[i2];
        f32x4 wv = w4[i2];
        CONSUME(lb, xv, wv);
    }
    // scalar tail (n % 4 == 0 for this shape; kept generic)
    for (int e2i = n4 * 4 + tid; e2i < n; e2i += T)
        ghm_elem(labels[e2i], logits[e2i], weights[e2i], G, C);

    // wave shuffle reduce, then cross-wave via (tiny) LDS
    #pragma unroll
    for (int off = 32; off > 0; off >>= 1) {
        #pragma unroll
        for (int b = 0; b < BINS; ++b) {
            C[b] += __shfl_down(C[b], off);
            G[b] += __shfl_down(G[b], off);
        }
    }
    __shared__ float redc[K1_THREADS / 64][BINS];
    __shared__ float redg[K1_THREADS / 64][BINS];
    const int wid = threadIdx.x >> 6, lane = threadIdx.x & 63;
    if (lane == 0) {
        #pragma unroll
        for (int b = 0; b < BINS; ++b) { redc[wid][b] = C[b]; redg[wid][b] = G[b]; }
    }
    __syncthreads();
    if (threadIdx.x < BINS) {
        float cc = 0.0f, gg = 0.0f;
        #pragma unroll
        for (int wv = 0; wv < K1_THREADS / 64; ++wv) {
            cc += redc[wv][threadIdx.x];
            gg += redg[wv][threadIdx.x];
        }
        partial[threadIdx.x * nb + blockIdx.x]          = cc;
        partial[(BINS + threadIdx.x) * nb + blockIdx.x] = gg;
    }
}

// Kernel 2: reduce nb columns, de-cumulate, finalize scalar (x ln2 rescale).
__global__ __launch_bounds__(1024) void ghm_final(
    const float* __restrict__ partial, float* __restrict__ out, int nb)
{
    const int tid = threadIdx.x;
    float acc[2 * BINS];
    #pragma unroll
    for (int b = 0; b < 2 * BINS; ++b) acc[b] = 0.0f;
    for (int j = tid; j < nb; j += 1024) {
        #pragma unroll
        for (int b = 0; b < 2 * BINS; ++b)
            acc[b] += partial[b * nb + j];
    }
    #pragma unroll
    for (int off = 32; off > 0; off >>= 1) {
        #pragma unroll
        for (int b = 0; b < 2 * BINS; ++b)
            acc[b] += __shfl_down(acc[b], off);
    }
    __shared__ float red[16][2 * BINS];
    const int wave = tid >> 6, lane = tid & 63;
    if (lane == 0) {
        #pragma unroll
        for (int b = 0; b < 2 * BINS; ++b) red[wave][b] = acc[b];
    }
    __syncthreads();
    if (tid == 0) {
        float cum_c[BINS], cum_g[BINS];
        #pragma unroll
        for (int b = 0; b < BINS; ++b) { cum_c[b] = 0.0f; cum_g[b] = 0.0f; }
        for (int wv = 0; wv < 16; ++wv) {
            #pragma unroll
            for (int b = 0; b < BINS; ++b) {
                cum_c[b] += red[wv][b];
                cum_g[b] += red[wv][BINS + b];
            }
        }
        float nn = 0.0f, res = 0.0f;
        #pragma unroll
        for (int b = 0; b < BINS; ++b) {
            float Cb = (b < BINS - 1) ? (cum_c[b] - cum_c[b + 1]) : cum_c[b];
            float Sb = (b < BINS - 1) ? (cum_g[b] - cum_g[b + 1]) : cum_g[b];
            if (Cb > 0.5f) { nn += 1.0f; res += Sb / Cb; }
        }
        res *= 0.69314718f;         // ln2: G was accumulated in log2 units
        if (nn > 0.0f) res /= nn;   // total_num cancels exactly
        out[0] = res;
    }
}

extern "C" void kernel_launch(void* const* d_in, const int* in_sizes, int n_in,
                              void* d_out, int out_size, void* d_ws, size_t ws_size,
                              hipStream_t stream) {
    const int*   labels  = (const int*)d_in[0];
    const float* logits  = (const float*)d_in[1];
    const float* weights = (const float*)d_in[2];
    float* out     = (float*)d_out;
    float* partial = (float*)d_ws;

    const int n  = in_sizes[0];
    const int n4 = n / 4;

    // ONLY change vs R13 (passed, 72.9 us): nb 1440 -> 2048.
    // 2048 blocks = 8 blocks/CU -> 32 waves/CU occupancy cap (R13 measured
    // 55-59% at 1440). Host-side constant only; kernel code byte-identical.
    int nb = 2048;
    const size_t row_bytes = 2 * BINS * sizeof(float);
    if (ws_size < row_bytes * 2048) nb = 1440;
    if (ws_size < row_bytes * 1440) nb = 720;
    if (ws_size < row_bytes * 720)  nb = 360;

    ghm_partial<<<nb, K1_THREADS, 0, stream>>>(labels, logits, weights, partial,
                                               n4, n, nb);
    ghm_final<<<1, 1024, 0, stream>>>(partial, out, nb);
}

// Round 16
// 74.410 us; speedup vs baseline: 1.0047x; 1.0047x over previous
//
#include <hip/hip_runtime.h>
#include <math.h>

#define BINS 10
#define K1_THREADS 256

typedef float f32x4 __attribute__((ext_vector_type(4)));
typedef int   i32x4 __attribute__((ext_vector_type(4)));

// Cumulative-threshold formulation in LOG2 space (R13-verified, absmax 0.0):
//   t = xs * log2(e);  bin >= b  <=>  t >= TH2[b] = log2(b/(10-b))
//   softplus(xs) = ln2 * [ max(t,0) + log2(1 + 2^(-|t|)) ]  = ln2 * bce2
// Final scalar rescaled by ln2 in kernel 2.
// Invalid elements poisoned t=-1e30: bce2 == 0 exactly, fails all thresholds.
// NOTE: this ghm_elem body (bool ge + ternary adds, float accumulators) is
// the ONLY idiom set that passes on this toolchain — float-mask+fmaf
// (R9-R11) and unsigned+=bool (R14) both SIGABRT. BYTE-IDENTICAL to R13.
__device__ __forceinline__ void ghm_elem(int y, float x, float w,
                                         float* __restrict__ G,
                                         float* __restrict__ C) {
    constexpr float TH2[10] = {
        0.0f,
        -3.16992500f,    // log2(1/9)
        -2.0f,           // log2(2/8)
        -1.22239242f,    // log2(3/7)
        -0.58496250f,    // log2(4/6)
         0.0f,           // log2(5/5)
         0.58496250f,
         1.22239242f,
         2.0f,
         3.16992500f };
    float t = x * 1.44269504f;                   // x * log2(e)
    t = __int_as_float(__float_as_int(t) ^ (y << 31));  // label==1 -> -t
    bool v = (w > 0.0f);
    t = v ? t : -1e30f;
    C[0] += v ? 1.0f : 0.0f;
    float e2   = exp2f(-fabsf(t));               // v_exp_f32, src mods fold
    float bce2 = fmaxf(t, 0.0f) + log2f(1.0f + e2);   // v_log_f32
    G[0] += bce2;
    #pragma unroll
    for (int b = 1; b < BINS; ++b) {
        bool ge = (t >= TH2[b]);
        C[b] += ge ? 1.0f : 0.0f;
        G[b] += ge ? bce2 : 0.0f;
    }
}

// Inline-asm loads: compiler cannot sink these (R6/R8 lesson).
#define GLOAD(dst, ptr) \
    asm volatile("global_load_dwordx4 %0, %1, off" : "=v"(dst) : "v"(ptr))

// Counted drain + scheduling fence (rule #18). HALF as many of these as R13:
// one fence per 8 consumed elements instead of per 4.
#define VMWAIT(N)                                              \
    do { asm volatile("s_waitcnt vmcnt(" #N ")" ::: "memory"); \
         __builtin_amdgcn_sched_barrier(0); } while (0)

#define CONSUME4(l, xv, wv)                       \
    do {                                          \
        ghm_elem(l[0], xv[0], wv[0], G, C);       \
        ghm_elem(l[1], xv[1], wv[1], G, C);       \
        ghm_elem(l[2], xv[2], wv[2], G, C);       \
        ghm_elem(l[3], xv[3], wv[3], G, C);       \
    } while (0)

// One set = 8 elements/thread = 6 dwordx4 loads (two stride-1-coalesced
// float4 positions j and j+T per stream).
#define ISSUE(S, base)                                             \
    do { const long _j = (base);                                   \
        GLOAD(l##S##0, lab4 + _j); GLOAD(l##S##1, lab4 + _j + T);  \
        GLOAD(x##S##0, log4 + _j); GLOAD(x##S##1, log4 + _j + T);  \
        GLOAD(w##S##0, w4   + _j); GLOAD(w##S##1, w4   + _j + T);  \
    } while (0)

#define CONSUME_SET(S)                            \
    do { CONSUME4(l##S##0, x##S##0, w##S##0);     \
         CONSUME4(l##S##1, x##S##1, w##S##1); } while (0)

// LB(256,4): 128-VGPR cap fits the 12 pinned vec4 tuples (48) + 20
// accumulators + addressing. 16 waves/CU — R15 proved more doesn't help.
__global__ __launch_bounds__(K1_THREADS, 4) void ghm_partial(
    const int*   __restrict__ labels,
    const float* __restrict__ logits,
    const float* __restrict__ weights,
    float*       __restrict__ partial,
    int n4, int n, int nb)
{
    const int tid = blockIdx.x * K1_THREADS + threadIdx.x;
    const int T   = gridDim.x * K1_THREADS;
    const long sbT = 2L * T;               // float4-stride of one superbatch

    float G[BINS], C[BINS];
    #pragma unroll
    for (int b = 0; b < BINS; ++b) { G[b] = 0.0f; C[b] = 0.0f; }

    const i32x4* lab4 = (const i32x4*)labels;
    const f32x4* log4 = (const f32x4*)logits;
    const f32x4* w4   = (const f32x4*)weights;

    const int nsb = (int)(n4 / sbT);       // uniform superbatches per thread
    int consumed4 = 0;                     // consumed float4 batches

    if (nsb >= 2) {
        i32x4 lA0, lA1, lB0, lB1;
        f32x4 xA0, xA1, xB0, xB1, wA0, wA1, wB0, wB1;

        ISSUE(A, tid);                     // 12 loads in flight
        ISSUE(B, tid + sbT);

        const int s = (nsb - 2) / 2;       // steady pair-iterations
        long nxt = 2L * sbT + tid;
        for (int it = 0; it < s; ++it) {
            VMWAIT(6);                     // set A drained (B's 6 outstanding)
            CONSUME_SET(A);
            ISSUE(A, nxt); nxt += sbT;
            VMWAIT(6);                     // set B drained
            CONSUME_SET(B);
            ISSUE(B, nxt); nxt += sbT;
        }
        VMWAIT(6); CONSUME_SET(A);
        VMWAIT(0); CONSUME_SET(B);         // clean vmcnt state
        consumed4 = 2 * (2 + 2 * s);
    }

    // leftover float4 batches (odd remainder / small-n fallback)
    for (long i2 = (long)tid + (long)consumed4 * T; i2 < n4; i2 += T) {
        i32x4 lb = lab4[i2];
        f32x4 xv = log4[i2];
        f32x4 wv = w4[i2];
        CONSUME4(lb, xv, wv);
    }
    // scalar tail (n % 4 == 0 for this shape; kept generic)
    for (int e2i = n4 * 4 + tid; e2i < n; e2i += T)
        ghm_elem(labels[e2i], logits[e2i], weights[e2i], G, C);

    // wave shuffle reduce, then cross-wave via (tiny) LDS
    #pragma unroll
    for (int off = 32; off > 0; off >>= 1) {
        #pragma unroll
        for (int b = 0; b < BINS; ++b) {
            C[b] += __shfl_down(C[b], off);
            G[b] += __shfl_down(G[b], off);
        }
    }
    __shared__ float redc[K1_THREADS / 64][BINS];
    __shared__ float redg[K1_THREADS / 64][BINS];
    const int wid = threadIdx.x >> 6, lane = threadIdx.x & 63;
    if (lane == 0) {
        #pragma unroll
        for (int b = 0; b < BINS; ++b) { redc[wid][b] = C[b]; redg[wid][b] = G[b]; }
    }
    __syncthreads();
    if (threadIdx.x < BINS) {
        float cc = 0.0f, gg = 0.0f;
        #pragma unroll
        for (int wv = 0; wv < K1_THREADS / 64; ++wv) {
            cc += redc[wv][threadIdx.x];
            gg += redg[wv][threadIdx.x];
        }
        partial[threadIdx.x * nb + blockIdx.x]          = cc;
        partial[(BINS + threadIdx.x) * nb + blockIdx.x] = gg;
    }
}

// Kernel 2: reduce nb columns, de-cumulate, finalize scalar (x ln2 rescale).
__global__ __launch_bounds__(1024) void ghm_final(
    const float* __restrict__ partial, float* __restrict__ out, int nb)
{
    const int tid = threadIdx.x;
    float acc[2 * BINS];
    #pragma unroll
    for (int b = 0; b < 2 * BINS; ++b) acc[b] = 0.0f;
    for (int j = tid; j < nb; j += 1024) {
        #pragma unroll
        for (int b = 0; b < 2 * BINS; ++b)
            acc[b] += partial[b * nb + j];
    }
    #pragma unroll
    for (int off = 32; off > 0; off >>= 1) {
        #pragma unroll
        for (int b = 0; b < 2 * BINS; ++b)
            acc[b] += __shfl_down(acc[b], off);
    }
    __shared__ float red[16][2 * BINS];
    const int wave = tid >> 6, lane = tid & 63;
    if (lane == 0) {
        #pragma unroll
        for (int b = 0; b < 2 * BINS; ++b) red[wave][b] = acc[b];
    }
    __syncthreads();
    if (tid == 0) {
        float cum_c[BINS], cum_g[BINS];
        #pragma unroll
        for (int b = 0; b < BINS; ++b) { cum_c[b] = 0.0f; cum_g[b] = 0.0f; }
        for (int wv = 0; wv < 16; ++wv) {
            #pragma unroll
            for (int b = 0; b < BINS; ++b) {
                cum_c[b] += red[wv][b];
                cum_g[b] += red[wv][BINS + b];
            }
        }
        float nn = 0.0f, res = 0.0f;
        #pragma unroll
        for (int b = 0; b < BINS; ++b) {
            float Cb = (b < BINS - 1) ? (cum_c[b] - cum_c[b + 1]) : cum_c[b];
            float Sb = (b < BINS - 1) ? (cum_g[b] - cum_g[b + 1]) : cum_g[b];
            if (Cb > 0.5f) { nn += 1.0f; res += Sb / Cb; }
        }
        res *= 0.69314718f;         // ln2: G was accumulated in log2 units
        if (nn > 0.0f) res /= nn;   // total_num cancels exactly
        out[0] = res;
    }
}

extern "C" void kernel_launch(void* const* d_in, const int* in_sizes, int n_in,
                              void* d_out, int out_size, void* d_ws, size_t ws_size,
                              hipStream_t stream) {
    const int*   labels  = (const int*)d_in[0];
    const float* logits  = (const float*)d_in[1];
    const float* weights = (const float*)d_in[2];
    float* out     = (float*)d_out;
    float* partial = (float*)d_ws;

    const int n  = in_sizes[0];
    const int n4 = n / 4;

    int nb = 1440;                 // T=368,640 -> 8 superbatches/thread exactly
    const size_t row_bytes = 2 * BINS * sizeof(float);
    if (ws_size < row_bytes * 1440) nb = 720;
    if (ws_size < row_bytes * 720)  nb = 360;

    ghm_partial<<<nb, K1_THREADS, 0, stream>>>(labels, logits, weights, partial,
                                               n4, n, nb);
    ghm_final<<<1, 1024, 0, stream>>>(partial, out, nb);
}

// Round 17
// 72.774 us; speedup vs baseline: 1.0273x; 1.0225x over previous
//
#include <hip/hip_runtime.h>
#include <math.h>

#define BINS 10
#define K1_THREADS 256

typedef float f32x4 __attribute__((ext_vector_type(4)));
typedef int   i32x4 __attribute__((ext_vector_type(4)));

// FINAL KERNEL — byte-exact restore of R13 (best measured: 72.9 us, absmax 0.0).
//
// Cumulative-threshold formulation in LOG2 space:
//   t = xs * log2(e);  bin >= b  <=>  t >= TH2[b] = log2(b/(10-b))
//   softplus(xs) = ln2 * [ max(t,0) + log2(1 + 2^(-|t|)) ]  = ln2 * bce2
// We accumulate bce2 (scaled) and multiply the final scalar by ln2 in k2.
// Invalid elements poisoned t=-1e30: bce2 == 0 exactly, fails all thresholds.
// exp2f/log2f are the NATIVE v_exp_f32/v_log_f32 ops (no range-scaling mul).
// NOTE: this ghm_elem body (bool ge + ternary adds, float accumulators) is
// the ONLY idiom set that passes on this toolchain — float-mask+fmaf (R9-R11)
// and unsigned+=bool (R14) both SIGABRT the harness. Do not deviate.
__device__ __forceinline__ void ghm_elem(int y, float x, float w,
                                         float* __restrict__ G,
                                         float* __restrict__ C) {
    constexpr float TH2[10] = {
        0.0f,
        -3.16992500f,    // log2(1/9)
        -2.0f,           // log2(2/8)
        -1.22239242f,    // log2(3/7)
        -0.58496250f,    // log2(4/6)
         0.0f,           // log2(5/5)
         0.58496250f,
         1.22239242f,
         2.0f,
         3.16992500f };
    float t = x * 1.44269504f;                   // x * log2(e)
    t = __int_as_float(__float_as_int(t) ^ (y << 31));  // label==1 -> -t
    bool v = (w > 0.0f);
    t = v ? t : -1e30f;
    C[0] += v ? 1.0f : 0.0f;
    float e2   = exp2f(-fabsf(t));               // v_exp_f32, src mods fold
    float bce2 = fmaxf(t, 0.0f) + log2f(1.0f + e2);   // v_log_f32
    G[0] += bce2;
    #pragma unroll
    for (int b = 1; b < BINS; ++b) {
        bool ge = (t >= TH2[b]);
        C[b] += ge ? 1.0f : 0.0f;
        G[b] += ge ? bce2 : 0.0f;
    }
}

// Inline-asm loads: the compiler CANNOT sink these to their uses, so the
// depth-3 pipeline actually stays in flight (R8-proven structure).
#define GLOAD(dst, ptr) \
    asm volatile("global_load_dwordx4 %0, %1, off" : "=v"(dst) : "v"(ptr))

// Counted drain + scheduling fence (rule #18).
#define VMWAIT(N)                                              \
    do { asm volatile("s_waitcnt vmcnt(" #N ")" ::: "memory"); \
         __builtin_amdgcn_sched_barrier(0); } while (0)

#define CONSUME(l, xv, wv)                        \
    do {                                          \
        ghm_elem(l[0], xv[0], wv[0], G, C);       \
        ghm_elem(l[1], xv[1], wv[1], G, C);       \
        ghm_elem(l[2], xv[2], wv[2], G, C);       \
        ghm_elem(l[3], xv[3], wv[3], G, C);       \
    } while (0)

__global__ __launch_bounds__(K1_THREADS, 6) void ghm_partial(
    const int*   __restrict__ labels,
    const float* __restrict__ logits,
    const float* __restrict__ weights,
    float*       __restrict__ partial,
    int n4, int n, int nb)
{
    const int tid = blockIdx.x * K1_THREADS + threadIdx.x;
    const int T   = gridDim.x * K1_THREADS;

    float G[BINS], C[BINS];
    #pragma unroll
    for (int b = 0; b < BINS; ++b) { G[b] = 0.0f; C[b] = 0.0f; }

    const i32x4* lab4 = (const i32x4*)labels;
    const f32x4* log4 = (const f32x4*)logits;
    const f32x4* w4   = (const f32x4*)weights;

    const int nfull = n4 / T;      // uniform full batches per thread
    int consumed = 0;

    if (nfull >= 3) {
        i32x4 lA, lB, lC;
        f32x4 xA, xB, xC, wA, wB, wC;
        long ia = tid;
        // prologue: 3 batches x 3 streams = 9 loads in flight
        GLOAD(lA, lab4 + ia);         GLOAD(xA, log4 + ia);         GLOAD(wA, w4 + ia);
        GLOAD(lB, lab4 + ia + T);     GLOAD(xB, log4 + ia + T);     GLOAD(wB, w4 + ia + T);
        GLOAD(lC, lab4 + ia + 2*T);   GLOAD(xC, log4 + ia + 2*T);   GLOAD(wC, w4 + ia + 2*T);

        const int s = (nfull - 3) / 3;    // steady iterations (3 batches each)
        long inx = ia + 3L * T;           // next issue index
        for (int it = 0; it < s; ++it) {
            VMWAIT(6);                    // oldest 3 (A) drained
            CONSUME(lA, xA, wA);
            GLOAD(lA, lab4 + inx); GLOAD(xA, log4 + inx); GLOAD(wA, w4 + inx);
            inx += T;
            VMWAIT(6);                    // B drained
            CONSUME(lB, xB, wB);
            GLOAD(lB, lab4 + inx); GLOAD(xB, log4 + inx); GLOAD(wB, w4 + inx);
            inx += T;
            VMWAIT(6);                    // C drained
            CONSUME(lC, xC, wC);
            GLOAD(lC, lab4 + inx); GLOAD(xC, log4 + inx); GLOAD(wC, w4 + inx);
            inx += T;
        }
        VMWAIT(6); CONSUME(lA, xA, wA);
        VMWAIT(3); CONSUME(lB, xB, wB);
        VMWAIT(0); CONSUME(lC, xC, wC);   // all drained -> clean vmcnt state
        consumed = 3 + 3 * s;
    }

    // leftover batches (ragged region when n4 % T != 0) — plain loads
    for (long i2 = (long)tid + (long)consumed * T; i2 < n4; i2 += T) {
        i32x4 lb = lab4[i2];
        f32x4 xv = log4[i2];
        f32x4 wv = w4[i2];
        CONSUME(lb, xv, wv);
    }
    // scalar tail (n % 4 == 0 for this shape; kept generic)
    for (int e2i = n4 * 4 + tid; e2i < n; e2i += T)
        ghm_elem(labels[e2i], logits[e2i], weights[e2i], G, C);

    // wave shuffle reduce, then cross-wave via (tiny) LDS
    #pragma unroll
    for (int off = 32; off > 0; off >>= 1) {
        #pragma unroll
        for (int b = 0; b < BINS; ++b) {
            C[b] += __shfl_down(C[b], off);
            G[b] += __shfl_down(G[b], off);
        }
    }
    __shared__ float redc[K1_THREADS / 64][BINS];
    __shared__ float redg[K1_THREADS / 64][BINS];
    const int wid = threadIdx.x >> 6, lane = threadIdx.x & 63;
    if (lane == 0) {
        #pragma unroll
        for (int b = 0; b < BINS; ++b) { redc[wid][b] = C[b]; redg[wid][b] = G[b]; }
    }
    __syncthreads();
    if (threadIdx.x < BINS) {
        float cc = 0.0f, gg = 0.0f;
        #pragma unroll
        for (int wv = 0; wv < K1_THREADS / 64; ++wv) {
            cc += redc[wv][threadIdx.x];
            gg += redg[wv][threadIdx.x];
        }
        partial[threadIdx.x * nb + blockIdx.x]          = cc;
        partial[(BINS + threadIdx.x) * nb + blockIdx.x] = gg;
    }
}

// Kernel 2: reduce nb columns, de-cumulate, finalize scalar (x ln2 rescale).
__global__ __launch_bounds__(1024) void ghm_final(
    const float* __restrict__ partial, float* __restrict__ out, int nb)
{
    const int tid = threadIdx.x;
    float acc[2 * BINS];
    #pragma unroll
    for (int b = 0; b < 2 * BINS; ++b) acc[b] = 0.0f;
    for (int j = tid; j < nb; j += 1024) {
        #pragma unroll
        for (int b = 0; b < 2 * BINS; ++b)
            acc[b] += partial[b * nb + j];
    }
    #pragma unroll
    for (int off = 32; off > 0; off >>= 1) {
        #pragma unroll
        for (int b = 0; b < 2 * BINS; ++b)
            acc[b] += __shfl_down(acc[b], off);
    }
    __shared__ float red[16][2 * BINS];
    const int wave = tid >> 6, lane = tid & 63;
    if (lane == 0) {
        #pragma unroll
        for (int b = 0; b < 2 * BINS; ++b) red[wave][b] = acc[b];
    }
    __syncthreads();
    if (tid == 0) {
        float cum_c[BINS], cum_g[BINS];
        #pragma unroll
        for (int b = 0; b < BINS; ++b) { cum_c[b] = 0.0f; cum_g[b] = 0.0f; }
        for (int wv = 0; wv < 16; ++wv) {
            #pragma unroll
            for (int b = 0; b < BINS; ++b) {
                cum_c[b] += red[wv][b];
                cum_g[b] += red[wv][BINS + b];
            }
        }
        float nn = 0.0f, res = 0.0f;
        #pragma unroll
        for (int b = 0; b < BINS; ++b) {
            float Cb = (b < BINS - 1) ? (cum_c[b] - cum_c[b + 1]) : cum_c[b];
            float Sb = (b < BINS - 1) ? (cum_g[b] - cum_g[b + 1]) : cum_g[b];
            if (Cb > 0.5f) { nn += 1.0f; res += Sb / Cb; }
        }
        res *= 0.69314718f;         // ln2: G was accumulated in log2 units
        if (nn > 0.0f) res /= nn;   // total_num cancels exactly
        out[0] = res;
    }
}

extern "C" void kernel_launch(void* const* d_in, const int* in_sizes, int n_in,
                              void* d_out, int out_size, void* d_ws, size_t ws_size,
                              hipStream_t stream) {
    const int*   labels  = (const int*)d_in[0];
    const float* logits  = (const float*)d_in[1];
    const float* weights = (const float*)d_in[2];
    float* out     = (float*)d_out;
    float* partial = (float*)d_ws;

    const int n  = in_sizes[0];
    const int n4 = n / 4;

    int nb = 1440;                     // T=368,640 -> nfull=16 for this shape
    const size_t row_bytes = 2 * BINS * sizeof(float);
    if (ws_size < row_bytes * 1440) nb = 720;
    if (ws_size < row_bytes * 720)  nb = 360;

    ghm_partial<<<nb, K1_THREADS, 0, stream>>>(labels, logits, weights, partial,
                                               n4, n, nb);
    ghm_final<<<1, 1024, 0, stream>>>(partial, out, nb);
}